// Round 3
// baseline (361.625 us; speedup 1.0000x reference)
//
#include <hip/hip_runtime.h>
#include <math.h>

// Fused CBAM spatial mask:
//   per timestep image (3 ch): maxpool3x3 + avgpool3x3 (pad 1) -> interleave (6 ch)
//   -> conv3x3 (6->1) + bias -> LeakyReLU(0.01) -> sigmoid -> broadcast to 3 ch.
// One thread computes a 4x4 block of mask pixels; all pooling + conv fused in
// registers (rolling 3-row window, separable row/col reductions). Single read
// of input, single write of output => memory-bound target ~201 MB traffic.
//
// Address audit (R2): max read idx = (BT*3-1)*65536 + 255*256 + 255 = last elem;
// max write idx likewise exactly the last out element; all float4 accesses are
// 16B-aligned (w0 % 4 == 0). No LDS, no d_ws use.

#define H 256
#define W 256

__global__ __launch_bounds__(256, 2)
void cbam_fused_kernel(const float* __restrict__ x,
                       const float* __restrict__ cw,
                       const float* __restrict__ cb,
                       float* __restrict__ out)
{
    const int tid = threadIdx.x;
    const int tx = tid & 15;          // 16 threads across -> 64 cols
    const int ty = tid >> 4;          // 16 threads down   -> 64 rows
    const int w0 = blockIdx.x * 64 + tx * 4;   // first output col of this thread
    const int h0 = blockIdx.y * 64 + ty * 4;   // first output row of this thread
    const int bt = blockIdx.z;                 // fused B*T index

    const float bias = cb[0];

    float acc[4][4];
    #pragma unroll
    for (int o = 0; o < 4; ++o)
        #pragma unroll
        for (int j = 0; j < 4; ++j)
            acc[o][j] = 0.0f;

    // Fast path iff the 12-col aligned load span [w0-4, w0+8) is fully in-bounds.
    const bool colfast = (w0 >= 4) && (w0 <= 248);

    #pragma unroll 1
    for (int c = 0; c < 3; ++c) {
        const float* ch = x + (size_t)(bt * 3 + c) * (H * W);

        // conv weights for this channel: ic=2c is maxpool plane, 2c+1 is avgpool
        // plane; fold the 1/9 of count_include_pad avgpool into the weights.
        float wm[9], wa[9];
        #pragma unroll
        for (int k = 0; k < 9; ++k) {
            wm[k] = cw[(2 * c) * 9 + k];
            wa[k] = cw[(2 * c + 1) * 9 + k] * (1.0f / 9.0f);
        }

        // rolling 3-row window of per-row column-window reductions (6 windows)
        float rmax[3][6], rsum[3][6];

        #pragma unroll
        for (int r = 0; r < 8; ++r) {          // input rows h0-2 .. h0+5
            const int gr = h0 - 2 + r;
            const bool rowok = (gr >= 0) && (gr < H);

            float vm[12], vs[12];              // vm: -inf for OOB, vs: 0 for OOB
            if (rowok && colfast) {
                const float4* p = (const float4*)(ch + (size_t)gr * W + (w0 - 4));
                #pragma unroll
                for (int i = 0; i < 3; ++i) {
                    float4 q = p[i];
                    vm[i * 4 + 0] = q.x; vm[i * 4 + 1] = q.y;
                    vm[i * 4 + 2] = q.z; vm[i * 4 + 3] = q.w;
                }
                #pragma unroll
                for (int i = 0; i < 12; ++i) vs[i] = vm[i];
            } else if (rowok) {
                #pragma unroll
                for (int i = 0; i < 12; ++i) {
                    const int gc = w0 - 4 + i;
                    const bool ok = (gc >= 0) && (gc < W);
                    const float v = ok ? ch[(size_t)gr * W + gc] : 0.0f;
                    vs[i] = v;
                    vm[i] = ok ? v : -INFINITY;
                }
            } else {
                #pragma unroll
                for (int i = 0; i < 12; ++i) { vs[i] = 0.0f; vm[i] = -INFINITY; }
            }

            // row reduction: 6 column windows (pooled cols w0-1 .. w0+4)
            #pragma unroll
            for (int j = 0; j < 6; ++j) {
                rmax[r % 3][j] = fmaxf(fmaxf(vm[j + 2], vm[j + 3]), vm[j + 4]);
                rsum[r % 3][j] = vs[j + 2] + vs[j + 3] + vs[j + 4];
            }

            if (r >= 2) {
                const int p_ = r - 2;              // pooled row index 0..5
                const int gpr = h0 - 1 + p_;
                const bool prow_ok = (gpr >= 0) && (gpr < H);

                float pm[6], ps[6];
                #pragma unroll
                for (int j = 0; j < 6; ++j) {
                    // all 3 rows of the rolling buffer form the 3x3 window
                    float m = fmaxf(fmaxf(rmax[0][j], rmax[1][j]), rmax[2][j]);
                    float s = rsum[0][j] + rsum[1][j] + rsum[2][j];
                    const int gpc = w0 - 1 + j;
                    const bool ok = prow_ok && (gpc >= 0) && (gpc < W);
                    pm[j] = ok ? m : 0.0f;   // conv zero-padding on pooled map
                    ps[j] = ok ? s : 0.0f;
                }

                // conv: pooled row p_ feeds output rows o = p_-2 .. p_ (kh = p_-o)
                #pragma unroll
                for (int o = 0; o < 4; ++o) {
                    const int kh = p_ - o;
                    if (kh < 0 || kh > 2) continue;
                    #pragma unroll
                    for (int ow = 0; ow < 4; ++ow) {
                        float a = acc[o][ow];
                        #pragma unroll
                        for (int kw = 0; kw < 3; ++kw) {
                            a = fmaf(wm[kh * 3 + kw], pm[ow + kw], a);
                            a = fmaf(wa[kh * 3 + kw], ps[ow + kw], a);
                        }
                        acc[o][ow] = a;
                    }
                }
            }
        }
    }

    // epilogue: bias -> LeakyReLU -> sigmoid -> broadcast to the 3 channels
    #pragma unroll
    for (int o = 0; o < 4; ++o) {
        float4 res;
        float* rp = (float*)&res;
        #pragma unroll
        for (int ow = 0; ow < 4; ++ow) {
            float y = acc[o][ow] + bias;
            y = (y >= 0.0f) ? y : 0.01f * y;
            rp[ow] = 1.0f / (1.0f + expf(-y));   // precise exp: memory-bound, costs ~0
        }
        const size_t rowoff = (size_t)(h0 + o) * W + w0;
        const size_t plane = (size_t)(H * W);
        float* ob = out + (size_t)(bt * 3) * plane + rowoff;
        #pragma unroll
        for (int cc = 0; cc < 3; ++cc) {
            *(float4*)(ob + (size_t)cc * plane) = res;
        }
    }
}

extern "C" void kernel_launch(void* const* d_in, const int* in_sizes, int n_in,
                              void* d_out, int out_size, void* d_ws, size_t ws_size,
                              hipStream_t stream) {
    const float* x  = (const float*)d_in[0];
    const float* cw = (const float*)d_in[1];   // [1,6,3,3] = 54 floats
    const float* cb = (const float*)d_in[2];   // [1]
    float* out = (float*)d_out;

    const int BT_in  = in_sizes[0] / (3 * H * W);   // 128 for reference shapes
    const int BT_out = out_size    / (3 * H * W);

    // Defensive: refuse to launch on any shape mismatch rather than fault.
    if (BT_in <= 0 || BT_in != BT_out ||
        in_sizes[0] != BT_in * 3 * H * W || out_size != BT_in * 3 * H * W ||
        n_in < 3 || in_sizes[1] < 54 || in_sizes[2] < 1)
        return;

    dim3 grid(W / 64, H / 64, BT_in);          // 4 x 4 x 128 = 2048 blocks
    dim3 block(256);
    cbam_fused_kernel<<<grid, block, 0, stream>>>(x, cw, cb, out);
}

// Round 5
// 231.961 us; speedup vs baseline: 1.5590x; 1.5590x over previous
//
#include <hip/hip_runtime.h>
#include <math.h>

// Fused CBAM spatial mask, v2 (latency-bound fix):
//   thread = 1 output row x 4 cols; wave = 64 lanes = one full 256-col row.
//   block = 256 thr = 4 rows; grid = (H/4, B*T) = (64,128) = 8192 blocks.
// avgpool+conv collapsed into per-input-row effective weights (linear path);
// maxpool path uses a 3-pooled-row rolling register buffer. Weights pinned to
// SGPR via readfirstlane bit-cast. Target: <=64 VGPR, 8 waves/SIMD.

#define H 256
#define W 256
#define NEG_INF (-__builtin_inff())

__device__ __forceinline__ float uniform_f(float v) {
    // force wave-uniform float into an SGPR
    return __int_as_float(__builtin_amdgcn_readfirstlane(__float_as_int(v)));
}

__global__ __launch_bounds__(256, 6)
void cbam_fused_kernel(const float* __restrict__ x,
                       const float* __restrict__ cw,
                       const float* __restrict__ cb,
                       float* __restrict__ out)
{
    const int tid  = threadIdx.x;
    const int lane = tid & 63;            // cols lane*4 .. lane*4+3
    const int wy   = tid >> 6;            // 4 waves -> 4 consecutive rows
    const int row  = blockIdx.x * 4 + wy; // wave-uniform output row
    const int bt   = blockIdx.y;
    const int c0   = lane * 4;

    const bool lane0  = (lane == 0);
    const bool lane63 = (lane == 63);

    // pooled-row validity (conv zero-pad), wave-uniform
    const bool pv[3] = { row - 1 >= 0, true, row + 1 < H };

    float acc0 = 0.f, acc1 = 0.f, acc2 = 0.f, acc3 = 0.f;

    #pragma unroll 1
    for (int c = 0; c < 3; ++c) {
        const float* ch = x + (size_t)(bt * 3 + c) * (H * W);

        // max-plane conv weights (uniform -> SGPR)
        float wm[9];
        #pragma unroll
        for (int k = 0; k < 9; ++k)
            wm[k] = uniform_f(cw[(2 * c) * 9 + k]);

        // avg path: conv(avgpool(x)) is linear -> per-input-row effective
        // 1x3 stencils. wae[r+2][kw] = sum over pooled rows p in {r-1,r,r+1}
        // ∩ [-1,1], p valid, of conv_w_avg[p+1][kw] / 9.
        float wae[5][3];
        #pragma unroll
        for (int r = -2; r <= 2; ++r) {
            #pragma unroll
            for (int kw = 0; kw < 3; ++kw) {
                float s = 0.f;
                #pragma unroll
                for (int p = -1; p <= 1; ++p) {
                    if (p < r - 1 || p > r + 1) continue;   // compile-time
                    const float wv = cw[(2 * c + 1) * 9 + (p + 1) * 3 + kw] * (1.f / 9.f);
                    s += pv[p + 1] ? wv : 0.f;
                }
                wae[r + 2][kw] = uniform_f(s);
            }
        }

        // rolling pooled-max partials, q = p+1 for pooled rows p = -1,0,1
        float pm[3][6];
        #pragma unroll
        for (int q = 0; q < 3; ++q)
            #pragma unroll
            for (int j = 0; j < 6; ++j)
                pm[q][j] = NEG_INF;

        #pragma unroll
        for (int r = -2; r <= 2; ++r) {
            const int gr = row + r;
            if (gr >= 0 && gr < H) {                 // wave-uniform branch
                const float* rp = ch + (size_t)gr * W;
                // three aligned float4 chunks: cols c0-4.., c0.., c0+4..
                // boundary lanes clamp the address and mask the values.
                const float4 L = *(const float4*)(rp + (lane0  ? 0  : c0 - 4));
                const float4 M = *(const float4*)(rp + c0);
                const float4 R = *(const float4*)(rp + (lane63 ? c0 : c0 + 4));

                const float z2 = lane0  ? 0.f : L.z;      // col c0-2 (sum id 0)
                const float z3 = lane0  ? 0.f : L.w;      // col c0-1
                const float z8 = lane63 ? 0.f : R.x;      // col c0+4
                const float z9 = lane63 ? 0.f : R.y;      // col c0+5
                const float m2 = lane0  ? NEG_INF : L.z;  // max identity -inf
                const float m3 = lane0  ? NEG_INF : L.w;
                const float m8 = lane63 ? NEG_INF : R.x;
                const float m9 = lane63 ? NEG_INF : R.y;

                // 6 column windows j (pooled cols c0-1+j)
                float rm[6], rs[6];
                rm[0] = fmaxf(fmaxf(m2,  m3),  M.x);  rs[0] = z2 + z3 + M.x;
                rm[1] = fmaxf(fmaxf(m3,  M.x), M.y);  rs[1] = z3 + M.x + M.y;
                rm[2] = fmaxf(fmaxf(M.x, M.y), M.z);  rs[2] = M.x + M.y + M.z;
                rm[3] = fmaxf(fmaxf(M.y, M.z), M.w);  rs[3] = M.y + M.z + M.w;
                rm[4] = fmaxf(fmaxf(M.z, M.w), m8);   rs[4] = M.z + M.w + z8;
                rm[5] = fmaxf(fmaxf(M.w, m8),  m9);   rs[5] = M.w + z8 + z9;

                // pooled cols -1 / 256 are conv zero-pad -> kill windows 0/5
                rs[0] = lane0  ? 0.f : rs[0];
                rs[5] = lane63 ? 0.f : rs[5];

                // avg path: direct accumulate with effective weights
                const float w0 = wae[r + 2][0], w1 = wae[r + 2][1], w2 = wae[r + 2][2];
                acc0 = fmaf(w0, rs[0], fmaf(w1, rs[1], fmaf(w2, rs[2], acc0)));
                acc1 = fmaf(w0, rs[1], fmaf(w1, rs[2], fmaf(w2, rs[3], acc1)));
                acc2 = fmaf(w0, rs[2], fmaf(w1, rs[3], fmaf(w2, rs[4], acc2)));
                acc3 = fmaf(w0, rs[3], fmaf(w1, rs[4], fmaf(w2, rs[5], acc3)));

                // max path: row r feeds pooled rows p in {r-1,r,r+1} ∩ [-1,1]
                #pragma unroll
                for (int q = 0; q < 3; ++q) {
                    const int p = q - 1;
                    if (p < r - 1 || p > r + 1) continue;   // compile-time
                    #pragma unroll
                    for (int j = 0; j < 6; ++j)
                        pm[q][j] = fmaxf(pm[q][j], rm[j]);
                }
            }

            // pooled row p=r-1 is complete after input row r: conv-apply it
            if (r >= 0) {                                   // compile-time
                const int q = r;                            // = p+1
                if (pv[q]) {                                // wave-uniform
                    const float p0 = lane0  ? 0.f : pm[q][0];
                    const float p5 = lane63 ? 0.f : pm[q][5];
                    const float k0 = wm[q * 3 + 0], k1 = wm[q * 3 + 1], k2 = wm[q * 3 + 2];
                    acc0 = fmaf(k0, p0,       fmaf(k1, pm[q][1], fmaf(k2, pm[q][2], acc0)));
                    acc1 = fmaf(k0, pm[q][1], fmaf(k1, pm[q][2], fmaf(k2, pm[q][3], acc1)));
                    acc2 = fmaf(k0, pm[q][2], fmaf(k1, pm[q][3], fmaf(k2, pm[q][4], acc2)));
                    acc3 = fmaf(k0, pm[q][3], fmaf(k1, pm[q][4], fmaf(k2, p5,       acc3)));
                }
            }
        }
    }

    // epilogue: bias -> LeakyReLU -> sigmoid -> broadcast to 3 channels
    const float bias = uniform_f(cb[0]);
    float4 res;
    {
        float a[4] = { acc0, acc1, acc2, acc3 };
        float* rp = (float*)&res;
        #pragma unroll
        for (int i = 0; i < 4; ++i) {
            float y = a[i] + bias;
            y = (y >= 0.f) ? y : 0.01f * y;
            rp[i] = 1.f / (1.f + expf(-y));
        }
    }
    float* ob = out + (size_t)(bt * 3) * (H * W) + (size_t)row * W + c0;
    *(float4*)(ob)             = res;   // each wave: 1KB contiguous per plane
    *(float4*)(ob + H * W)     = res;
    *(float4*)(ob + 2 * H * W) = res;
}

extern "C" void kernel_launch(void* const* d_in, const int* in_sizes, int n_in,
                              void* d_out, int out_size, void* d_ws, size_t ws_size,
                              hipStream_t stream) {
    const float* x  = (const float*)d_in[0];
    const float* cw = (const float*)d_in[1];   // [1,6,3,3] = 54 floats
    const float* cb = (const float*)d_in[2];   // [1]
    float* out = (float*)d_out;

    const int BT_in  = in_sizes[0] / (3 * H * W);
    const int BT_out = out_size    / (3 * H * W);
    if (BT_in <= 0 || BT_in != BT_out ||
        in_sizes[0] != BT_in * 3 * H * W || out_size != BT_in * 3 * H * W ||
        n_in < 3 || in_sizes[1] < 54 || in_sizes[2] < 1)
        return;

    dim3 grid(H / 4, BT_in);        // 64 x 128 = 8192 blocks
    dim3 block(256);                // 4 waves; wave = one full output row
    cbam_fused_kernel<<<grid, block, 0, stream>>>(x, cw, cb, out);
}